// Round 1
// baseline (903.202 us; speedup 1.0000x reference)
//
#include <hip/hip_runtime.h>
#include <hip/hip_bf16.h>
#include <math.h>

#define F_IN 500
#define HID 32
#define NCLS 40

// ---------------- CSR build ----------------

__global__ void zero_kernel(int* p, int n) {
    int i = blockIdx.x * 256 + threadIdx.x;
    if (i < n) p[i] = 0;
}

__global__ void hist_kernel(const int* __restrict__ dst, int E, int* __restrict__ deg) {
    int e = blockIdx.x * 256 + threadIdx.x;
    if (e < E) atomicAdd(&deg[dst[e]], 1);
}

// single-block exclusive scan over deg[0..N-1] -> rowptr[0..N], copy to cursor
__global__ __launch_bounds__(1024) void scan_kernel(const int* __restrict__ deg,
                                                    int* __restrict__ rowptr,
                                                    int* __restrict__ cursor, int N) {
    __shared__ int wsum[16];
    __shared__ int chunk_total;
    int tid = threadIdx.x;
    int lane = tid & 63;
    int wid = tid >> 6;
    int running = 0;
    int nchunks = (N + 1023) >> 10;
    for (int c = 0; c < nchunks; ++c) {
        int idx = (c << 10) + tid;
        int v = (idx < N) ? deg[idx] : 0;
        int x = v;
        #pragma unroll
        for (int off = 1; off < 64; off <<= 1) {
            int y = __shfl_up(x, off);
            if (lane >= off) x += y;
        }
        if (lane == 63) wsum[wid] = x;
        __syncthreads();
        if (wid == 0) {
            int wv = (lane < 16) ? wsum[lane] : 0;
            #pragma unroll
            for (int off = 1; off < 16; off <<= 1) {
                int y = __shfl_up(wv, off);
                if (lane >= off) wv += y;
            }
            if (lane < 16) wsum[lane] = wv;
            if (lane == 15) chunk_total = wv;
        }
        __syncthreads();
        int wbase = (wid > 0) ? wsum[wid - 1] : 0;
        int excl = running + wbase + (x - v);
        if (idx < N) { rowptr[idx] = excl; cursor[idx] = excl; }
        running += chunk_total;
        __syncthreads();
    }
    if (tid == 0) rowptr[N] = running;
}

__global__ void scatter_kernel(const int* __restrict__ src, const int* __restrict__ dst,
                               int E, int* __restrict__ cursor, int* __restrict__ col) {
    int e = blockIdx.x * 256 + threadIdx.x;
    if (e < E) {
        int d = dst[e];
        int pos = atomicAdd(&cursor[d], 1);
        col[pos] = src[e];
    }
}

// ---------------- GEMM1: h1 = relu(x @ W1 + b1), [N,500]@[500,32] ----------------
// block = 256 threads; block tile = 256 rows x 32 cols; thread tile = 4 rows x 8 cols.
#define G1_KC 32

__global__ __launch_bounds__(256) void gemm1_kernel(const float* __restrict__ x,
                                                    const float* __restrict__ W1,
                                                    const float* __restrict__ b1,
                                                    float* __restrict__ h1, int N) {
    __shared__ float xs[256][G1_KC + 1];   // 33792 B, +1 pad
    __shared__ float w1s[G1_KC][32];       // 4096 B
    int tid = threadIdx.x;
    int ct = tid & 3;        // col group: cols ct*8 .. ct*8+7
    int rt = tid >> 2;       // row group: rows rt*4 .. rt*4+3
    int row0 = blockIdx.x * 256;

    float acc[4][8];
    #pragma unroll
    for (int q = 0; q < 4; ++q)
        #pragma unroll
        for (int j = 0; j < 8; ++j) acc[q][j] = 0.f;

    for (int kc = 0; kc < 512; kc += G1_KC) {
        // stage x tile: 256 rows x 32 k
        #pragma unroll
        for (int s = 0; s < 8; ++s) {
            int f4 = tid + (s << 8);          // 0..2047
            int row = f4 >> 3;
            int c4 = (f4 & 7) << 2;
            int gr = row0 + row;
            int k = kc + c4;
            float4 v = make_float4(0.f, 0.f, 0.f, 0.f);
            if (gr < N) {
                if (k + 3 < F_IN) {
                    v = *(const float4*)(x + (long)gr * F_IN + k);
                } else {
                    float t0 = (k + 0 < F_IN) ? x[(long)gr * F_IN + k + 0] : 0.f;
                    float t1 = (k + 1 < F_IN) ? x[(long)gr * F_IN + k + 1] : 0.f;
                    float t2 = (k + 2 < F_IN) ? x[(long)gr * F_IN + k + 2] : 0.f;
                    float t3 = (k + 3 < F_IN) ? x[(long)gr * F_IN + k + 3] : 0.f;
                    v = make_float4(t0, t1, t2, t3);
                }
            }
            xs[row][c4 + 0] = v.x;
            xs[row][c4 + 1] = v.y;
            xs[row][c4 + 2] = v.z;
            xs[row][c4 + 3] = v.w;
        }
        // stage W1 chunk: 32 k x 32 cols
        #pragma unroll
        for (int s = 0; s < 4; ++s) {
            int idx = tid + (s << 8);
            int kk = idx >> 5;
            int j = idx & 31;
            int k = kc + kk;
            w1s[kk][j] = (k < F_IN) ? W1[(long)k * 32 + j] : 0.f;
        }
        __syncthreads();

        #pragma unroll 4
        for (int kk = 0; kk < G1_KC; ++kk) {
            float4 wa = *(const float4*)&w1s[kk][ct * 8];
            float4 wb = *(const float4*)&w1s[kk][ct * 8 + 4];
            #pragma unroll
            for (int q = 0; q < 4; ++q) {
                float xv = xs[rt * 4 + q][kk];
                acc[q][0] += xv * wa.x;
                acc[q][1] += xv * wa.y;
                acc[q][2] += xv * wa.z;
                acc[q][3] += xv * wa.w;
                acc[q][4] += xv * wb.x;
                acc[q][5] += xv * wb.y;
                acc[q][6] += xv * wb.z;
                acc[q][7] += xv * wb.w;
            }
        }
        __syncthreads();
    }

    float4 ba = *(const float4*)(b1 + ct * 8);
    float4 bb = *(const float4*)(b1 + ct * 8 + 4);
    #pragma unroll
    for (int q = 0; q < 4; ++q) {
        int gr = row0 + rt * 4 + q;
        if (gr < N) {
            float4 oa, ob;
            oa.x = fmaxf(acc[q][0] + ba.x, 0.f);
            oa.y = fmaxf(acc[q][1] + ba.y, 0.f);
            oa.z = fmaxf(acc[q][2] + ba.z, 0.f);
            oa.w = fmaxf(acc[q][3] + ba.w, 0.f);
            ob.x = fmaxf(acc[q][4] + bb.x, 0.f);
            ob.y = fmaxf(acc[q][5] + bb.y, 0.f);
            ob.z = fmaxf(acc[q][6] + bb.z, 0.f);
            ob.w = fmaxf(acc[q][7] + bb.w, 0.f);
            float* op = h1 + (long)gr * 32 + ct * 8;
            *(float4*)op = oa;
            *(float4*)(op + 4) = ob;
        }
    }
}

// ---------------- row L2-norm: rn[i] = rsqrt(sum(h[i]^2) + 1e-12) ----------------
__global__ __launch_bounds__(256) void rownorm_kernel(const float* __restrict__ h,
                                                      float* __restrict__ rn, int N) {
    int half = threadIdx.x >> 5;
    int lane = threadIdx.x & 31;
    int i = blockIdx.x * 8 + half;
    if (i >= N) return;
    float v = h[(i << 5) + lane];
    float ss = v * v;
    ss += __shfl_xor(ss, 1);
    ss += __shfl_xor(ss, 2);
    ss += __shfl_xor(ss, 4);
    ss += __shfl_xor(ss, 8);
    ss += __shfl_xor(ss, 16);
    if (lane == 0) rn[i] = rsqrtf(ss + 1e-12f);
}

// ---------------- AGNN conv: one half-wave (32 lanes) per dst node ----------------
// softmax shift-invariance: use constant shift |beta| instead of segment_max
// (logits = beta*cos in [-|beta|,|beta|], so exp in [e^-2|b|, 1] — safe).
__global__ __launch_bounds__(256) void conv_kernel(const float* __restrict__ h,
                                                   const float* __restrict__ rn,
                                                   const int* __restrict__ rowptr,
                                                   const int* __restrict__ col,
                                                   const float* __restrict__ betaPtr,
                                                   float* __restrict__ out,
                                                   float* __restrict__ rnOut, int N) {
    int half = threadIdx.x >> 5;
    int lane = threadIdx.x & 31;
    int i = blockIdx.x * 8 + half;
    if (i >= N) return;

    float beta = betaPtr ? betaPtr[0] : 1.0f;
    float mshift = fabsf(beta);

    float hi = h[(i << 5) + lane];
    float ri = rn[i];
    int e0 = rowptr[i];
    int e1 = rowptr[i + 1];

    float s = 0.f;
    float acc = 0.f;

    int j = (e0 < e1) ? col[e0] : 0;
    for (int e = e0; e < e1; ++e) {
        int jn = (e + 1 < e1) ? col[e + 1] : 0;   // prefetch next col
        float hj = h[(j << 5) + lane];
        float rj = rn[j];
        float d = hi * hj;
        d += __shfl_xor(d, 1);
        d += __shfl_xor(d, 2);
        d += __shfl_xor(d, 4);
        d += __shfl_xor(d, 8);
        d += __shfl_xor(d, 16);
        float w = __expf(beta * ri * rj * d - mshift);
        s += w;
        acc += w * hj;
        j = jn;
    }

    float o = acc / (s + 1e-16f);
    out[(i << 5) + lane] = o;

    float ss = o * o;
    ss += __shfl_xor(ss, 1);
    ss += __shfl_xor(ss, 2);
    ss += __shfl_xor(ss, 4);
    ss += __shfl_xor(ss, 8);
    ss += __shfl_xor(ss, 16);
    if (lane == 0) rnOut[i] = rsqrtf(ss + 1e-12f);
}

// ---------------- GEMM2: out = h3 @ W2 + b2, [N,32]@[32,40] ----------------
__global__ __launch_bounds__(256) void gemm2_kernel(const float* __restrict__ h3,
                                                    const float* __restrict__ W2,
                                                    const float* __restrict__ b2,
                                                    float* __restrict__ out, int N) {
    __shared__ float w2s[HID * NCLS];
    __shared__ float b2s[NCLS];
    for (int i = threadIdx.x; i < HID * NCLS; i += 256) w2s[i] = W2[i];
    if (threadIdx.x < NCLS) b2s[threadIdx.x] = b2[threadIdx.x];
    __syncthreads();

    int idx = blockIdx.x * 256 + threadIdx.x;
    if (idx >= N * NCLS) return;
    int n = idx / NCLS;
    int c = idx - n * NCLS;

    const float4* hp = (const float4*)(h3 + (long)n * 32);
    float acc = b2s[c];
    #pragma unroll
    for (int k4 = 0; k4 < 8; ++k4) {
        float4 hv = hp[k4];
        acc += hv.x * w2s[(k4 * 4 + 0) * NCLS + c];
        acc += hv.y * w2s[(k4 * 4 + 1) * NCLS + c];
        acc += hv.z * w2s[(k4 * 4 + 2) * NCLS + c];
        acc += hv.w * w2s[(k4 * 4 + 3) * NCLS + c];
    }
    out[idx] = acc;
}

// ---------------- launch ----------------

extern "C" void kernel_launch(void* const* d_in, const int* in_sizes, int n_in,
                              void* d_out, int out_size, void* d_ws, size_t ws_size,
                              hipStream_t stream) {
    const float* x     = (const float*)d_in[0];
    const float* W1    = (const float*)d_in[1];
    const float* b1    = (const float*)d_in[2];
    const float* W2    = (const float*)d_in[3];
    const float* b2    = (const float*)d_in[4];
    const float* beta2 = (const float*)d_in[5];
    const int*   ei    = (const int*)d_in[6];

    int N = in_sizes[0] / F_IN;        // 100000
    int E = in_sizes[6] / 2;           // 1700000
    const int* src = ei;
    const int* dst = ei + E;
    float* out = (float*)d_out;

    // workspace carve (all 256B aligned)
    char* p = (char*)d_ws;
    auto alloc = [&](size_t bytes) -> void* {
        void* r = (void*)p;
        p += (bytes + 255) & ~(size_t)255;
        return r;
    };
    float* h1  = (float*)alloc((size_t)N * 32 * 4);
    float* h2  = (float*)alloc((size_t)N * 32 * 4);
    float* h3  = (float*)alloc((size_t)N * 32 * 4);
    float* rn1 = (float*)alloc((size_t)N * 4);
    float* rn2 = (float*)alloc((size_t)N * 4);
    float* rn3 = (float*)alloc((size_t)N * 4);
    int* deg    = (int*)alloc((size_t)N * 4);
    int* rowptr = (int*)alloc((size_t)(N + 1) * 4);
    int* cursor = (int*)alloc((size_t)N * 4);
    int* col    = (int*)alloc((size_t)E * 4);

    int ethreads = (E + 255) / 256;
    int nthreads = (N + 255) / 256;

    // CSR build (graph identical for both convs)
    zero_kernel<<<nthreads, 256, 0, stream>>>(deg, N);
    hist_kernel<<<ethreads, 256, 0, stream>>>(dst, E, deg);
    scan_kernel<<<1, 1024, 0, stream>>>(deg, rowptr, cursor, N);
    scatter_kernel<<<ethreads, 256, 0, stream>>>(src, dst, E, cursor, col);

    // feature pipeline
    gemm1_kernel<<<(N + 255) / 256, 256, 0, stream>>>(x, W1, b1, h1, N);
    rownorm_kernel<<<(N + 7) / 8, 256, 0, stream>>>(h1, rn1, N);
    conv_kernel<<<(N + 7) / 8, 256, 0, stream>>>(h1, rn1, rowptr, col, nullptr, h2, rn2, N);
    conv_kernel<<<(N + 7) / 8, 256, 0, stream>>>(h2, rn2, rowptr, col, beta2, h3, rn3, N);
    gemm2_kernel<<<(N * NCLS + 255) / 256, 256, 0, stream>>>(h3, W2, b2, out, N);
}

// Round 2
// 802.318 us; speedup vs baseline: 1.1257x; 1.1257x over previous
//
#include <hip/hip_runtime.h>
#include <hip/hip_bf16.h>
#include <math.h>

#define F_IN 500
#define HID 32
#define NCLS 40

// ---------------- CSR build ----------------

__global__ void zero_kernel(int* p, int n) {
    int i = blockIdx.x * 256 + threadIdx.x;
    if (i < n) p[i] = 0;
}

__global__ void hist_kernel(const int* __restrict__ dst, int E, int* __restrict__ deg) {
    int e = blockIdx.x * 256 + threadIdx.x;
    if (e < E) atomicAdd(&deg[dst[e]], 1);
}

// single-block exclusive scan over deg[0..N-1] -> rowptr[0..N], copy to cursor
__global__ __launch_bounds__(1024) void scan_kernel(const int* __restrict__ deg,
                                                    int* __restrict__ rowptr,
                                                    int* __restrict__ cursor, int N) {
    __shared__ int wsum[16];
    __shared__ int chunk_total;
    int tid = threadIdx.x;
    int lane = tid & 63;
    int wid = tid >> 6;
    int running = 0;
    int nchunks = (N + 1023) >> 10;
    for (int c = 0; c < nchunks; ++c) {
        int idx = (c << 10) + tid;
        int v = (idx < N) ? deg[idx] : 0;
        int x = v;
        #pragma unroll
        for (int off = 1; off < 64; off <<= 1) {
            int y = __shfl_up(x, off);
            if (lane >= off) x += y;
        }
        if (lane == 63) wsum[wid] = x;
        __syncthreads();
        if (wid == 0) {
            int wv = (lane < 16) ? wsum[lane] : 0;
            #pragma unroll
            for (int off = 1; off < 16; off <<= 1) {
                int y = __shfl_up(wv, off);
                if (lane >= off) wv += y;
            }
            if (lane < 16) wsum[lane] = wv;
            if (lane == 15) chunk_total = wv;
        }
        __syncthreads();
        int wbase = (wid > 0) ? wsum[wid - 1] : 0;
        int excl = running + wbase + (x - v);
        if (idx < N) { rowptr[idx] = excl; cursor[idx] = excl; }
        running += chunk_total;
        __syncthreads();
    }
    if (tid == 0) rowptr[N] = running;
}

// scatter: CSR col[] plus rowidx[] (dst per CSR slot, for edge-parallel pass)
__global__ void scatter_kernel(const int* __restrict__ src, const int* __restrict__ dst,
                               int E, int* __restrict__ cursor, int* __restrict__ col,
                               int* __restrict__ rowidx) {
    int e = blockIdx.x * 256 + threadIdx.x;
    if (e < E) {
        int d = dst[e];
        int pos = atomicAdd(&cursor[d], 1);
        col[pos] = src[e];
        rowidx[pos] = d;
    }
}

// ---------------- GEMM1: h1 = relu(x @ W1 + b1), fused row L2-norm ----------------
// 128 rows/block (782 blocks), 256 threads, thread tile = 2 rows x 8 cols.
__global__ __launch_bounds__(256) void gemm1_kernel(const float* __restrict__ x,
                                                    const float* __restrict__ W1,
                                                    const float* __restrict__ b1,
                                                    float* __restrict__ h1,
                                                    float* __restrict__ rn, int N) {
    __shared__ float xs[128][33];   // +1 pad
    __shared__ float w1s[32][32];
    int tid = threadIdx.x;
    int ct = tid & 3;        // col group: cols ct*8 .. ct*8+7
    int rt = tid >> 2;       // row group: rows rt*2 .. rt*2+1
    int row0 = blockIdx.x * 128;

    float acc[2][8];
    #pragma unroll
    for (int q = 0; q < 2; ++q)
        #pragma unroll
        for (int j = 0; j < 8; ++j) acc[q][j] = 0.f;

    for (int kc = 0; kc < 512; kc += 32) {
        // stage x tile: 128 rows x 32 k   (256 threads x 4 float4)
        #pragma unroll
        for (int s = 0; s < 4; ++s) {
            int f4 = tid + (s << 8);          // 0..1023
            int row = f4 >> 3;                // 0..127
            int c4 = (f4 & 7) << 2;
            int gr = row0 + row;
            int k = kc + c4;
            float4 v = make_float4(0.f, 0.f, 0.f, 0.f);
            if (gr < N && k < F_IN)           // F_IN=500 is 4-divisible: no partial float4
                v = *(const float4*)(x + (long)gr * F_IN + k);
            xs[row][c4 + 0] = v.x;
            xs[row][c4 + 1] = v.y;
            xs[row][c4 + 2] = v.z;
            xs[row][c4 + 3] = v.w;
        }
        // stage W1 chunk: 32 k x 32 cols
        #pragma unroll
        for (int s = 0; s < 4; ++s) {
            int idx = tid + (s << 8);
            int kk = idx >> 5;
            int j = idx & 31;
            int k = kc + kk;
            w1s[kk][j] = (k < F_IN) ? W1[(long)k * 32 + j] : 0.f;
        }
        __syncthreads();

        #pragma unroll 8
        for (int kk = 0; kk < 32; ++kk) {
            float4 wa = *(const float4*)&w1s[kk][ct * 8];
            float4 wb = *(const float4*)&w1s[kk][ct * 8 + 4];
            float x0 = xs[rt * 2 + 0][kk];
            float x1 = xs[rt * 2 + 1][kk];
            acc[0][0] += x0 * wa.x; acc[0][1] += x0 * wa.y;
            acc[0][2] += x0 * wa.z; acc[0][3] += x0 * wa.w;
            acc[0][4] += x0 * wb.x; acc[0][5] += x0 * wb.y;
            acc[0][6] += x0 * wb.z; acc[0][7] += x0 * wb.w;
            acc[1][0] += x1 * wa.x; acc[1][1] += x1 * wa.y;
            acc[1][2] += x1 * wa.z; acc[1][3] += x1 * wa.w;
            acc[1][4] += x1 * wb.x; acc[1][5] += x1 * wb.y;
            acc[1][6] += x1 * wb.z; acc[1][7] += x1 * wb.w;
        }
        __syncthreads();
    }

    float4 ba = *(const float4*)(b1 + ct * 8);
    float4 bb = *(const float4*)(b1 + ct * 8 + 4);
    #pragma unroll
    for (int q = 0; q < 2; ++q) {
        int gr = row0 + rt * 2 + q;
        float4 oa, ob;
        oa.x = fmaxf(acc[q][0] + ba.x, 0.f);
        oa.y = fmaxf(acc[q][1] + ba.y, 0.f);
        oa.z = fmaxf(acc[q][2] + ba.z, 0.f);
        oa.w = fmaxf(acc[q][3] + ba.w, 0.f);
        ob.x = fmaxf(acc[q][4] + bb.x, 0.f);
        ob.y = fmaxf(acc[q][5] + bb.y, 0.f);
        ob.z = fmaxf(acc[q][6] + bb.z, 0.f);
        ob.w = fmaxf(acc[q][7] + bb.w, 0.f);
        // fused row-norm: reduce sumsq across the 4 ct threads (consecutive lanes)
        float ss = oa.x * oa.x + oa.y * oa.y + oa.z * oa.z + oa.w * oa.w
                 + ob.x * ob.x + ob.y * ob.y + ob.z * ob.z + ob.w * ob.w;
        ss += __shfl_xor(ss, 1);
        ss += __shfl_xor(ss, 2);
        if (gr < N) {
            float* op = h1 + (long)gr * 32 + ct * 8;
            *(float4*)op = oa;
            *(float4*)(op + 4) = ob;
            if (ct == 0) rn[gr] = rsqrtf(ss + 1e-12f);
        }
    }
}

// ---------------- conv pass 1: edge-parallel attention weights ----------------
// 8 lanes per CSR slot; w[e] = exp(beta*cos(i,j) - |beta|)  (softmax shift-invariance,
// logits in [-|beta|,|beta|] so constant shift replaces segment_max exactly).
__global__ __launch_bounds__(256) void edgew_kernel(const float* __restrict__ h,
                                                    const float* __restrict__ rn,
                                                    const int* __restrict__ col,
                                                    const int* __restrict__ rowidx,
                                                    const float* __restrict__ betaPtr,
                                                    float* __restrict__ wA, int E) {
    int sub = threadIdx.x & 7;
    int slot = blockIdx.x * 32 + (threadIdx.x >> 3);
    if (slot >= E) return;
    float beta = betaPtr ? betaPtr[0] : 1.0f;
    int i = rowidx[slot];
    int j = col[slot];
    float4 a = *(const float4*)(h + ((long)i << 5) + (sub << 2));
    float4 b = *(const float4*)(h + ((long)j << 5) + (sub << 2));
    float d = a.x * b.x + a.y * b.y + a.z * b.z + a.w * b.w;
    d += __shfl_xor(d, 1);
    d += __shfl_xor(d, 2);
    d += __shfl_xor(d, 4);
    float w = __expf(beta * rn[i] * rn[j] * d - fabsf(beta));
    if (sub == 0) wA[slot] = w;
}

// ---------------- conv pass 2: node-parallel weighted aggregate ----------------
// 8 lanes per node, float4 per lane; 4-deep unroll for independent gathers.
__global__ __launch_bounds__(256) void aggregate_kernel(const float* __restrict__ h,
                                                        const float* __restrict__ wA,
                                                        const int* __restrict__ rowptr,
                                                        const int* __restrict__ col,
                                                        float* __restrict__ out,
                                                        float* __restrict__ rnOut, int N) {
    int sub = threadIdx.x & 7;
    int i = blockIdx.x * 32 + (threadIdx.x >> 3);
    if (i >= N) return;
    int e0 = rowptr[i];
    int e1 = rowptr[i + 1];
    float4 acc = make_float4(0.f, 0.f, 0.f, 0.f);
    float s = 0.f;
    long lsub = (long)(sub << 2);
    int e = e0;
    for (; e + 4 <= e1; e += 4) {
        int j0 = col[e + 0], j1 = col[e + 1], j2 = col[e + 2], j3 = col[e + 3];
        float w0 = wA[e + 0], w1 = wA[e + 1], w2 = wA[e + 2], w3 = wA[e + 3];
        float4 v0 = *(const float4*)(h + ((long)j0 << 5) + lsub);
        float4 v1 = *(const float4*)(h + ((long)j1 << 5) + lsub);
        float4 v2 = *(const float4*)(h + ((long)j2 << 5) + lsub);
        float4 v3 = *(const float4*)(h + ((long)j3 << 5) + lsub);
        s += w0 + w1 + w2 + w3;
        acc.x += w0 * v0.x + w1 * v1.x + w2 * v2.x + w3 * v3.x;
        acc.y += w0 * v0.y + w1 * v1.y + w2 * v2.y + w3 * v3.y;
        acc.z += w0 * v0.z + w1 * v1.z + w2 * v2.z + w3 * v3.z;
        acc.w += w0 * v0.w + w1 * v1.w + w2 * v2.w + w3 * v3.w;
    }
    for (; e < e1; ++e) {
        int j = col[e];
        float w = wA[e];
        float4 v = *(const float4*)(h + ((long)j << 5) + lsub);
        s += w;
        acc.x += w * v.x; acc.y += w * v.y; acc.z += w * v.z; acc.w += w * v.w;
    }
    float inv = 1.f / (s + 1e-16f);
    float4 o;
    o.x = acc.x * inv; o.y = acc.y * inv; o.z = acc.z * inv; o.w = acc.w * inv;
    *(float4*)(out + ((long)i << 5) + lsub) = o;
    if (rnOut) {
        float ss = o.x * o.x + o.y * o.y + o.z * o.z + o.w * o.w;
        ss += __shfl_xor(ss, 1);
        ss += __shfl_xor(ss, 2);
        ss += __shfl_xor(ss, 4);
        if (sub == 0) rnOut[i] = rsqrtf(ss + 1e-12f);
    }
}

// ---------------- GEMM2: out = h3 @ W2 + b2, [N,32]@[32,40] ----------------
__global__ __launch_bounds__(256) void gemm2_kernel(const float* __restrict__ h3,
                                                    const float* __restrict__ W2,
                                                    const float* __restrict__ b2,
                                                    float* __restrict__ out, int N) {
    __shared__ float w2s[HID * NCLS];
    __shared__ float b2s[NCLS];
    for (int i = threadIdx.x; i < HID * NCLS; i += 256) w2s[i] = W2[i];
    if (threadIdx.x < NCLS) b2s[threadIdx.x] = b2[threadIdx.x];
    __syncthreads();

    int idx = blockIdx.x * 256 + threadIdx.x;
    if (idx >= N * NCLS) return;
    int n = idx / NCLS;
    int c = idx - n * NCLS;

    const float4* hp = (const float4*)(h3 + (long)n * 32);
    float acc = b2s[c];
    #pragma unroll
    for (int k4 = 0; k4 < 8; ++k4) {
        float4 hv = hp[k4];
        acc += hv.x * w2s[(k4 * 4 + 0) * NCLS + c];
        acc += hv.y * w2s[(k4 * 4 + 1) * NCLS + c];
        acc += hv.z * w2s[(k4 * 4 + 2) * NCLS + c];
        acc += hv.w * w2s[(k4 * 4 + 3) * NCLS + c];
    }
    out[idx] = acc;
}

// ---------------- launch ----------------

extern "C" void kernel_launch(void* const* d_in, const int* in_sizes, int n_in,
                              void* d_out, int out_size, void* d_ws, size_t ws_size,
                              hipStream_t stream) {
    const float* x     = (const float*)d_in[0];
    const float* W1    = (const float*)d_in[1];
    const float* b1    = (const float*)d_in[2];
    const float* W2    = (const float*)d_in[3];
    const float* b2    = (const float*)d_in[4];
    const float* beta2 = (const float*)d_in[5];
    const int*   ei    = (const int*)d_in[6];

    int N = in_sizes[0] / F_IN;        // 100000
    int E = in_sizes[6] / 2;           // 1700000
    const int* src = ei;
    const int* dst = ei + E;
    float* out = (float*)d_out;

    // workspace carve (256B aligned)
    char* p = (char*)d_ws;
    auto alloc = [&](size_t bytes) -> void* {
        void* r = (void*)p;
        p += (bytes + 255) & ~(size_t)255;
        return r;
    };
    float* h1  = (float*)alloc((size_t)N * 32 * 4);
    float* h2  = (float*)alloc((size_t)N * 32 * 4);
    float* rn1 = (float*)alloc((size_t)N * 4);
    float* rn2 = (float*)alloc((size_t)N * 4);
    int* deg    = (int*)alloc((size_t)N * 4);
    int* rowptr = (int*)alloc((size_t)(N + 1) * 4);
    int* cursor = (int*)alloc((size_t)N * 4);
    int* col    = (int*)alloc((size_t)E * 4);
    int* rowidx = (int*)alloc((size_t)E * 4);
    float* wA   = (float*)alloc((size_t)E * 4);
    float* h3   = h1;                  // conv2 output reuses h1 (free by then)

    int eblocks  = (E + 255) / 256;
    int nblocks  = (N + 255) / 256;
    int e8blocks = (E + 31) / 32;      // edge-parallel, 8 lanes/edge
    int n8blocks = (N + 31) / 32;      // node-parallel, 8 lanes/node

    // CSR build (graph identical for both convs)
    zero_kernel<<<nblocks, 256, 0, stream>>>(deg, N);
    hist_kernel<<<eblocks, 256, 0, stream>>>(dst, E, deg);
    scan_kernel<<<1, 1024, 0, stream>>>(deg, rowptr, cursor, N);
    scatter_kernel<<<eblocks, 256, 0, stream>>>(src, dst, E, cursor, col, rowidx);

    // feature pipeline
    gemm1_kernel<<<(N + 127) / 128, 256, 0, stream>>>(x, W1, b1, h1, rn1, N);

    edgew_kernel<<<e8blocks, 256, 0, stream>>>(h1, rn1, col, rowidx, nullptr, wA, E);
    aggregate_kernel<<<n8blocks, 256, 0, stream>>>(h1, wA, rowptr, col, h2, rn2, N);

    edgew_kernel<<<e8blocks, 256, 0, stream>>>(h2, rn2, col, rowidx, beta2, wA, E);
    aggregate_kernel<<<n8blocks, 256, 0, stream>>>(h2, wA, rowptr, col, h3, nullptr, N);

    gemm2_kernel<<<(N * NCLS + 255) / 256, 256, 0, stream>>>(h3, W2, b2, out, N);
}

// Round 3
// 610.664 us; speedup vs baseline: 1.4791x; 1.3138x over previous
//
#include <hip/hip_runtime.h>
#include <hip/hip_bf16.h>
#include <math.h>

#define F_IN 500
#define HID 32
#define NCLS 40

// ---------------- CSR build ----------------

__global__ void hist_kernel(const int* __restrict__ dst, int E, int* __restrict__ deg) {
    int e = blockIdx.x * 256 + threadIdx.x;
    if (e < E) atomicAdd(&deg[dst[e]], 1);
}

// pass 1: per-block local exclusive scan (1024 elems/block) + block totals
__global__ __launch_bounds__(1024) void scan_local_kernel(const int* __restrict__ deg,
                                                          int* __restrict__ rowptr,
                                                          int* __restrict__ blocksum, int N) {
    __shared__ int wsum[16];
    int tid = threadIdx.x;
    int lane = tid & 63;
    int wid = tid >> 6;
    int idx = blockIdx.x * 1024 + tid;
    int v = (idx < N) ? deg[idx] : 0;
    int x = v;
    #pragma unroll
    for (int off = 1; off < 64; off <<= 1) {
        int y = __shfl_up(x, off);
        if (lane >= off) x += y;
    }
    if (lane == 63) wsum[wid] = x;
    __syncthreads();
    if (wid == 0 && lane < 16) {
        int wv = wsum[lane];
        #pragma unroll
        for (int off = 1; off < 16; off <<= 1) {
            int y = __shfl_up(wv, off);
            if (lane >= off) wv += y;
        }
        wsum[lane] = wv;
    }
    __syncthreads();
    int base = (wid > 0) ? wsum[wid - 1] : 0;
    if (idx < N) rowptr[idx] = base + x - v;
    if (tid == 0) blocksum[blockIdx.x] = wsum[15];
}

// pass 2: exclusive-scan the (<=128) block totals in-place; write rowptr[N]
__global__ __launch_bounds__(128) void scan_offsets_kernel(int* __restrict__ blocksum,
                                                           int* __restrict__ rowptrN, int nb) {
    __shared__ int ws[2];
    int tid = threadIdx.x;
    int lane = tid & 63;
    int wid = tid >> 6;
    int v = (tid < nb) ? blocksum[tid] : 0;
    int x = v;
    #pragma unroll
    for (int off = 1; off < 64; off <<= 1) {
        int y = __shfl_up(x, off);
        if (lane >= off) x += y;
    }
    if (lane == 63) ws[wid] = x;
    __syncthreads();
    int base = (wid == 1) ? ws[0] : 0;
    int excl = base + x - v;
    if (tid < nb) blocksum[tid] = excl;
    if (tid == nb - 1) *rowptrN = excl + v;
}

// pass 3: add block offsets; produce cursor copy
__global__ __launch_bounds__(1024) void scan_add_kernel(const int* __restrict__ blocksum,
                                                        int* __restrict__ rowptr,
                                                        int* __restrict__ cursor, int N) {
    int idx = blockIdx.x * 1024 + threadIdx.x;
    if (idx < N) {
        int v = rowptr[idx] + blocksum[blockIdx.x];
        rowptr[idx] = v;
        cursor[idx] = v;
    }
}

__global__ void scatter_kernel(const int* __restrict__ src, const int* __restrict__ dst,
                               int E, int* __restrict__ cursor, int* __restrict__ col) {
    int e = blockIdx.x * 256 + threadIdx.x;
    if (e < E) {
        int pos = atomicAdd(&cursor[dst[e]], 1);
        col[pos] = src[e];
    }
}

// ---------------- GEMM1: h1 = relu(x @ W1 + b1), fused row L2-norm ----------------
// 128 rows/block, 256 threads, thread tile = 2 rows x 8 cols.
// Software-pipelined: next K-chunk prefetched to REGISTERS during compute;
// ds_write after barrier -> the barrier's vmcnt(0) drain lands after a full
// compute phase, hiding HBM latency (fix for 19% VALUBusy in round 2).
__global__ __launch_bounds__(256) void gemm1_kernel(const float* __restrict__ x,
                                                    const float* __restrict__ W1,
                                                    const float* __restrict__ b1,
                                                    float* __restrict__ h1,
                                                    float* __restrict__ rn, int N) {
    __shared__ float xs[128][33];   // +1 pad
    __shared__ float w1s[32][32];
    int tid = threadIdx.x;
    int ct = tid & 3;        // col group: cols ct*8 .. ct*8+7
    int rt = tid >> 2;       // row group: rows rt*2 .. rt*2+1
    long row0 = (long)blockIdx.x * 128;

    float acc[2][8];
    #pragma unroll
    for (int q = 0; q < 2; ++q)
        #pragma unroll
        for (int j = 0; j < 8; ++j) acc[q][j] = 0.f;

    float4 xr[4];
    float w1r[4];

    // prefetch chunk 0
    #pragma unroll
    for (int s = 0; s < 4; ++s) {
        int f4 = tid + (s << 8);
        int row = f4 >> 3;
        int c4 = (f4 & 7) << 2;
        long gr = row0 + row;
        xr[s] = make_float4(0.f, 0.f, 0.f, 0.f);
        if (gr < N && c4 < F_IN) xr[s] = *(const float4*)(x + gr * F_IN + c4);
        int idx = tid + (s << 8);
        w1r[s] = W1[(long)(idx >> 5) * 32 + (idx & 31)];
    }

    for (int kc = 0; kc < 512; kc += 32) {
        __syncthreads();   // prev compute done (drains the prefetch loads too,
                           // but they've had a full compute phase in flight)
        #pragma unroll
        for (int s = 0; s < 4; ++s) {
            int f4 = tid + (s << 8);
            int row = f4 >> 3;
            int c4 = (f4 & 7) << 2;
            xs[row][c4 + 0] = xr[s].x;
            xs[row][c4 + 1] = xr[s].y;
            xs[row][c4 + 2] = xr[s].z;
            xs[row][c4 + 3] = xr[s].w;
            int idx = tid + (s << 8);
            w1s[idx >> 5][idx & 31] = w1r[s];
        }
        __syncthreads();

        int kn = kc + 32;
        if (kn < 512) {
            #pragma unroll
            for (int s = 0; s < 4; ++s) {
                int f4 = tid + (s << 8);
                int row = f4 >> 3;
                int c4 = (f4 & 7) << 2;
                long gr = row0 + row;
                int k = kn + c4;
                xr[s] = make_float4(0.f, 0.f, 0.f, 0.f);
                if (gr < N && k < F_IN) xr[s] = *(const float4*)(x + gr * F_IN + k);
                int idx = tid + (s << 8);
                int kk = kn + (idx >> 5);
                w1r[s] = (kk < F_IN) ? W1[(long)kk * 32 + (idx & 31)] : 0.f;
            }
        }

        #pragma unroll 8
        for (int kk = 0; kk < 32; ++kk) {
            float4 wa = *(const float4*)&w1s[kk][ct * 8];
            float4 wb = *(const float4*)&w1s[kk][ct * 8 + 4];
            float x0 = xs[rt * 2 + 0][kk];
            float x1 = xs[rt * 2 + 1][kk];
            acc[0][0] += x0 * wa.x; acc[0][1] += x0 * wa.y;
            acc[0][2] += x0 * wa.z; acc[0][3] += x0 * wa.w;
            acc[0][4] += x0 * wb.x; acc[0][5] += x0 * wb.y;
            acc[0][6] += x0 * wb.z; acc[0][7] += x0 * wb.w;
            acc[1][0] += x1 * wa.x; acc[1][1] += x1 * wa.y;
            acc[1][2] += x1 * wa.z; acc[1][3] += x1 * wa.w;
            acc[1][4] += x1 * wb.x; acc[1][5] += x1 * wb.y;
            acc[1][6] += x1 * wb.z; acc[1][7] += x1 * wb.w;
        }
    }

    float4 ba = *(const float4*)(b1 + ct * 8);
    float4 bb = *(const float4*)(b1 + ct * 8 + 4);
    #pragma unroll
    for (int q = 0; q < 2; ++q) {
        long gr = row0 + rt * 2 + q;
        float4 oa, ob;
        oa.x = fmaxf(acc[q][0] + ba.x, 0.f);
        oa.y = fmaxf(acc[q][1] + ba.y, 0.f);
        oa.z = fmaxf(acc[q][2] + ba.z, 0.f);
        oa.w = fmaxf(acc[q][3] + ba.w, 0.f);
        ob.x = fmaxf(acc[q][4] + bb.x, 0.f);
        ob.y = fmaxf(acc[q][5] + bb.y, 0.f);
        ob.z = fmaxf(acc[q][6] + bb.z, 0.f);
        ob.w = fmaxf(acc[q][7] + bb.w, 0.f);
        float ss = oa.x * oa.x + oa.y * oa.y + oa.z * oa.z + oa.w * oa.w
                 + ob.x * ob.x + ob.y * ob.y + ob.z * ob.z + ob.w * ob.w;
        ss += __shfl_xor(ss, 1);
        ss += __shfl_xor(ss, 2);
        if (gr < N) {
            float* op = h1 + gr * 32 + ct * 8;
            *(float4*)op = oa;
            *(float4*)(op + 4) = ob;
            if (ct == 0) rn[gr] = rsqrtf(ss + 1e-12f);
        }
    }
}

// ---------------- fused AGNN conv: weights + aggregate in one pass ----------------
// 8 lanes per node; per edge: gather h[j] (float4/lane), dot via 3 shfl_xor,
// w = exp(beta*cos - |beta|) (softmax shift-invariance: logits in [-|b|,|b|]),
// accumulate s += w, acc += w*h[j]. Unroll 4 for independent gather chains.
__global__ __launch_bounds__(256) void conv_kernel(const float* __restrict__ h,
                                                   const float* __restrict__ rn,
                                                   const int* __restrict__ rowptr,
                                                   const int* __restrict__ col,
                                                   const float* __restrict__ betaPtr,
                                                   float* __restrict__ out,
                                                   float* __restrict__ rnOut, int N) {
    int sub = threadIdx.x & 7;
    int i = blockIdx.x * 32 + (threadIdx.x >> 3);
    if (i >= N) return;
    float beta = betaPtr ? betaPtr[0] : 1.0f;
    float shift = fabsf(beta);
    long lsub = (long)(sub << 2);
    float4 hi = *(const float4*)(h + ((long)i << 5) + lsub);
    float bri = beta * rn[i];
    int e0 = rowptr[i];
    int e1 = rowptr[i + 1];

    float s = 0.f;
    float4 acc = make_float4(0.f, 0.f, 0.f, 0.f);
    int e = e0;
    for (; e + 4 <= e1; e += 4) {
        int j0 = col[e + 0], j1 = col[e + 1], j2 = col[e + 2], j3 = col[e + 3];
        float r0 = rn[j0], r1 = rn[j1], r2 = rn[j2], r3 = rn[j3];
        float4 v0 = *(const float4*)(h + ((long)j0 << 5) + lsub);
        float4 v1 = *(const float4*)(h + ((long)j1 << 5) + lsub);
        float4 v2 = *(const float4*)(h + ((long)j2 << 5) + lsub);
        float4 v3 = *(const float4*)(h + ((long)j3 << 5) + lsub);
        float d0 = hi.x * v0.x + hi.y * v0.y + hi.z * v0.z + hi.w * v0.w;
        float d1 = hi.x * v1.x + hi.y * v1.y + hi.z * v1.z + hi.w * v1.w;
        float d2 = hi.x * v2.x + hi.y * v2.y + hi.z * v2.z + hi.w * v2.w;
        float d3 = hi.x * v3.x + hi.y * v3.y + hi.z * v3.z + hi.w * v3.w;
        d0 += __shfl_xor(d0, 1); d1 += __shfl_xor(d1, 1);
        d2 += __shfl_xor(d2, 1); d3 += __shfl_xor(d3, 1);
        d0 += __shfl_xor(d0, 2); d1 += __shfl_xor(d1, 2);
        d2 += __shfl_xor(d2, 2); d3 += __shfl_xor(d3, 2);
        d0 += __shfl_xor(d0, 4); d1 += __shfl_xor(d1, 4);
        d2 += __shfl_xor(d2, 4); d3 += __shfl_xor(d3, 4);
        float w0 = __expf(bri * r0 * d0 - shift);
        float w1 = __expf(bri * r1 * d1 - shift);
        float w2 = __expf(bri * r2 * d2 - shift);
        float w3 = __expf(bri * r3 * d3 - shift);
        s += (w0 + w1) + (w2 + w3);
        acc.x += w0 * v0.x + w1 * v1.x + w2 * v2.x + w3 * v3.x;
        acc.y += w0 * v0.y + w1 * v1.y + w2 * v2.y + w3 * v3.y;
        acc.z += w0 * v0.z + w1 * v1.z + w2 * v2.z + w3 * v3.z;
        acc.w += w0 * v0.w + w1 * v1.w + w2 * v2.w + w3 * v3.w;
    }
    for (; e < e1; ++e) {
        int j = col[e];
        float rj = rn[j];
        float4 v = *(const float4*)(h + ((long)j << 5) + lsub);
        float d = hi.x * v.x + hi.y * v.y + hi.z * v.z + hi.w * v.w;
        d += __shfl_xor(d, 1);
        d += __shfl_xor(d, 2);
        d += __shfl_xor(d, 4);
        float w = __expf(bri * rj * d - shift);
        s += w;
        acc.x += w * v.x; acc.y += w * v.y; acc.z += w * v.z; acc.w += w * v.w;
    }

    float inv = 1.f / (s + 1e-16f);
    float4 o = make_float4(acc.x * inv, acc.y * inv, acc.z * inv, acc.w * inv);
    *(float4*)(out + ((long)i << 5) + lsub) = o;
    if (rnOut) {
        float ss = o.x * o.x + o.y * o.y + o.z * o.z + o.w * o.w;
        ss += __shfl_xor(ss, 1);
        ss += __shfl_xor(ss, 2);
        ss += __shfl_xor(ss, 4);
        if (sub == 0) rnOut[i] = rsqrtf(ss + 1e-12f);
    }
}

// ---------------- GEMM2: out = h3 @ W2 + b2, [N,32]@[32,40] ----------------
__global__ __launch_bounds__(256) void gemm2_kernel(const float* __restrict__ h3,
                                                    const float* __restrict__ W2,
                                                    const float* __restrict__ b2,
                                                    float* __restrict__ out, int N) {
    __shared__ float w2s[HID * NCLS];
    __shared__ float b2s[NCLS];
    for (int i = threadIdx.x; i < HID * NCLS; i += 256) w2s[i] = W2[i];
    if (threadIdx.x < NCLS) b2s[threadIdx.x] = b2[threadIdx.x];
    __syncthreads();

    int idx = blockIdx.x * 256 + threadIdx.x;
    if (idx >= N * NCLS) return;
    int n = idx / NCLS;
    int c = idx - n * NCLS;

    const float4* hp = (const float4*)(h3 + (long)n * 32);
    float acc = b2s[c];
    #pragma unroll
    for (int k4 = 0; k4 < 8; ++k4) {
        float4 hv = hp[k4];
        acc += hv.x * w2s[(k4 * 4 + 0) * NCLS + c];
        acc += hv.y * w2s[(k4 * 4 + 1) * NCLS + c];
        acc += hv.z * w2s[(k4 * 4 + 2) * NCLS + c];
        acc += hv.w * w2s[(k4 * 4 + 3) * NCLS + c];
    }
    out[idx] = acc;
}

// ---------------- launch ----------------

extern "C" void kernel_launch(void* const* d_in, const int* in_sizes, int n_in,
                              void* d_out, int out_size, void* d_ws, size_t ws_size,
                              hipStream_t stream) {
    const float* x     = (const float*)d_in[0];
    const float* W1    = (const float*)d_in[1];
    const float* b1    = (const float*)d_in[2];
    const float* W2    = (const float*)d_in[3];
    const float* b2    = (const float*)d_in[4];
    const float* beta2 = (const float*)d_in[5];
    const int*   ei    = (const int*)d_in[6];

    int N = in_sizes[0] / F_IN;        // 100000
    int E = in_sizes[6] / 2;           // 1700000
    const int* src = ei;
    const int* dst = ei + E;
    float* out = (float*)d_out;

    // workspace carve (256B aligned)
    char* p = (char*)d_ws;
    auto alloc = [&](size_t bytes) -> void* {
        void* r = (void*)p;
        p += (bytes + 255) & ~(size_t)255;
        return r;
    };
    float* h1  = (float*)alloc((size_t)N * 32 * 4);
    float* h2  = (float*)alloc((size_t)N * 32 * 4);
    float* rn1 = (float*)alloc((size_t)N * 4);
    float* rn2 = (float*)alloc((size_t)N * 4);
    int* deg      = (int*)alloc((size_t)N * 4);
    int* rowptr   = (int*)alloc((size_t)(N + 1) * 4);
    int* cursor   = (int*)alloc((size_t)N * 4);
    int* col      = (int*)alloc((size_t)E * 4);
    int* blocksum = (int*)alloc(1024 * 4);
    float* h3   = h1;                  // conv2 output reuses h1 (free by then)

    int eblocks = (E + 255) / 256;
    int sblocks = (N + 1023) / 1024;   // scan blocks (98)
    int cblocks = (N + 31) / 32;       // conv: 8 lanes/node

    // gemm1 first: x is L3-warm right after the harness input restore
    gemm1_kernel<<<(N + 127) / 128, 256, 0, stream>>>(x, W1, b1, h1, rn1, N);

    // CSR build (graph identical for both convs)
    hipMemsetAsync(deg, 0, (size_t)N * 4, stream);
    hist_kernel<<<eblocks, 256, 0, stream>>>(dst, E, deg);
    scan_local_kernel<<<sblocks, 1024, 0, stream>>>(deg, rowptr, blocksum, N);
    scan_offsets_kernel<<<1, 128, 0, stream>>>(blocksum, rowptr + N, sblocks);
    scan_add_kernel<<<sblocks, 1024, 0, stream>>>(blocksum, rowptr, cursor, N);
    scatter_kernel<<<eblocks, 256, 0, stream>>>(src, dst, E, cursor, col);

    // fused convs
    conv_kernel<<<cblocks, 256, 0, stream>>>(h1, rn1, rowptr, col, nullptr, h2, rn2, N);
    conv_kernel<<<cblocks, 256, 0, stream>>>(h2, rn2, rowptr, col, beta2, h3, nullptr, N);

    gemm2_kernel<<<(N * NCLS + 255) / 256, 256, 0, stream>>>(h3, W2, b2, out, N);
}

// Round 4
// 503.403 us; speedup vs baseline: 1.7942x; 1.2131x over previous
//
#include <hip/hip_runtime.h>
#include <math.h>

#define F_IN 500
#define HID 32
#define NCLS 40

// CSR radix build: bucket = 256 consecutive dst nodes. Requires N <= 131072
// (src packs in 17 bits, local dst in 9 -> one int per staged edge).
#define NPB 256
#define MAXB 512
#define EPB 16384

// ---------------- phase 1a: per-bucket edge counts (LDS-aggregated) ----------------
__global__ __launch_bounds__(256) void csr_count_kernel(const int* __restrict__ dst, int E,
                                                        int* __restrict__ gcnt, int nb) {
    __shared__ int cnt[MAXB];
    int tid = threadIdx.x;
    for (int i = tid; i < MAXB; i += 256) cnt[i] = 0;
    __syncthreads();
    long e0 = (long)blockIdx.x * EPB;
    #pragma unroll 4
    for (int k = 0; k < EPB / 256; ++k) {
        long e = e0 + tid + k * 256;
        if (e < E) atomicAdd(&cnt[dst[e] >> 8], 1);
    }
    __syncthreads();
    for (int b = tid; b < nb; b += 256)
        if (cnt[b]) atomicAdd(&gcnt[b], cnt[b]);
}

// ---------------- phase 1b: exclusive scan of bucket counts (1 block) ----------------
__global__ __launch_bounds__(512) void csr_bscan_kernel(const int* __restrict__ gcnt,
                                                        int* __restrict__ bucketptr,
                                                        int* __restrict__ bcur, int nb) {
    __shared__ int wsum[8];
    int tid = threadIdx.x, lane = tid & 63, wid = tid >> 6;
    int v = (tid < nb) ? gcnt[tid] : 0;
    int x = v;
    #pragma unroll
    for (int off = 1; off < 64; off <<= 1) {
        int y = __shfl_up(x, off);
        if (lane >= off) x += y;
    }
    if (lane == 63) wsum[wid] = x;
    __syncthreads();
    if (wid == 0 && lane < 8) {
        int wv = wsum[lane];
        #pragma unroll
        for (int off = 1; off < 8; off <<= 1) {
            int y = __shfl_up(wv, off);
            if (lane >= off) wv += y;
        }
        wsum[lane] = wv;
    }
    __syncthreads();
    int excl = ((wid > 0) ? wsum[wid - 1] : 0) + x - v;
    if (tid < nb) { bucketptr[tid] = excl; bcur[tid] = excl; }
    if (tid == nb - 1) bucketptr[nb] = excl + v;
}

// ---------------- phase 1c: LDS-bin edges by bucket, write staged runs ----------------
__global__ __launch_bounds__(512) void csr_bin_kernel(const int* __restrict__ src,
                                                      const int* __restrict__ dst, int E,
                                                      int* __restrict__ bcur,
                                                      int* __restrict__ gstage, int nb) {
    __shared__ int cnt[MAXB], off[MAXB], cur[MAXB], gbase[MAXB];
    __shared__ int stage[EPB];
    __shared__ int wsum[8];
    int tid = threadIdx.x, lane = tid & 63, wid = tid >> 6;
    cnt[tid] = 0;
    __syncthreads();
    long e0 = (long)blockIdx.x * EPB;
    #pragma unroll 4
    for (int k = 0; k < EPB / 512; ++k) {
        long e = e0 + tid + k * 512;
        if (e < E) atomicAdd(&cnt[dst[e] >> 8], 1);
    }
    __syncthreads();
    int v = cnt[tid];
    int x = v;
    #pragma unroll
    for (int o = 1; o < 64; o <<= 1) {
        int y = __shfl_up(x, o);
        if (lane >= o) x += y;
    }
    if (lane == 63) wsum[wid] = x;
    __syncthreads();
    if (wid == 0 && lane < 8) {
        int wv = wsum[lane];
        #pragma unroll
        for (int o = 1; o < 8; o <<= 1) {
            int y = __shfl_up(wv, o);
            if (lane >= o) wv += y;
        }
        wsum[lane] = wv;
    }
    __syncthreads();
    int excl = ((wid > 0) ? wsum[wid - 1] : 0) + x - v;
    off[tid] = excl;
    cur[tid] = excl;
    if (v) gbase[tid] = atomicAdd(&bcur[tid], v);
    __syncthreads();
    #pragma unroll 4
    for (int k = 0; k < EPB / 512; ++k) {
        long e = e0 + tid + k * 512;
        if (e < E) {
            int dd = dst[e];
            int b = dd >> 8;
            int w = src[e] | ((dd & 255) << 17);
            int p = atomicAdd(&cur[b], 1);
            stage[p] = w;
        }
    }
    __syncthreads();
    // copy per-bucket runs to atomically-reserved global staging (coalesced bursts)
    for (int b = wid; b < nb; b += 8) {
        int c = cnt[b];
        int lo = off[b], go = gbase[b];
        for (int k = lane; k < c; k += 64) gstage[go + k] = stage[lo + k];
    }
}

// ---------------- phase 2: per-bucket rowptr + col scatter (single-writer) ----------
__global__ __launch_bounds__(256) void csr_scatter_kernel(const int* __restrict__ bucketptr,
                                                          const int* __restrict__ gstage,
                                                          int* __restrict__ rowptr,
                                                          int* __restrict__ col, int N, int nb) {
    __shared__ int cur[NPB];
    __shared__ int wsum[4];
    int tid = threadIdx.x, lane = tid & 63, wid = tid >> 6;
    int b = blockIdx.x;
    int node0 = b << 8;
    int ebase = bucketptr[b], eend = bucketptr[b + 1];
    cur[tid] = 0;
    __syncthreads();
    for (int e = ebase + tid; e < eend; e += 256)
        atomicAdd(&cur[((unsigned)gstage[e]) >> 17], 1);
    __syncthreads();
    int v = cur[tid];
    int x = v;
    #pragma unroll
    for (int o = 1; o < 64; o <<= 1) {
        int y = __shfl_up(x, o);
        if (lane >= o) x += y;
    }
    if (lane == 63) wsum[wid] = x;
    __syncthreads();
    if (tid == 0) {
        int a0 = wsum[0], a1 = wsum[1], a2 = wsum[2];
        wsum[0] = 0; wsum[1] = a0; wsum[2] = a0 + a1; wsum[3] = a0 + a1 + a2;
    }
    __syncthreads();
    int start = ebase + wsum[wid] + x - v;       // exclusive prefix = this node's CSR start
    if (node0 + tid < N) rowptr[node0 + tid] = start;
    cur[tid] = start;
    __syncthreads();
    for (int e = ebase + tid; e < eend; e += 256) {
        unsigned w = (unsigned)gstage[e];
        int p = atomicAdd(&cur[w >> 17], 1);
        col[p] = (int)(w & 0x1FFFFu);            // bucket col span ~17 KB: L2-resident, 1 writer
    }
    if (b == nb - 1 && tid == 0) rowptr[N] = eend;
}

// ---------------- GEMM1: h1 = relu(x @ W1 + b1), fused row L2-norm ----------------
// 128 rows/block, 256 threads, thread tile = 2 rows x 8 cols; register prefetch pipeline.
__global__ __launch_bounds__(256) void gemm1_kernel(const float* __restrict__ x,
                                                    const float* __restrict__ W1,
                                                    const float* __restrict__ b1,
                                                    float* __restrict__ h1,
                                                    float* __restrict__ rn, int N) {
    __shared__ float xs[128][33];   // +1 pad
    __shared__ float w1s[32][32];
    int tid = threadIdx.x;
    int ct = tid & 3;
    int rt = tid >> 2;
    long row0 = (long)blockIdx.x * 128;

    float acc[2][8];
    #pragma unroll
    for (int q = 0; q < 2; ++q)
        #pragma unroll
        for (int j = 0; j < 8; ++j) acc[q][j] = 0.f;

    float4 xr[4];
    float w1r[4];

    #pragma unroll
    for (int s = 0; s < 4; ++s) {
        int f4 = tid + (s << 8);
        int row = f4 >> 3;
        int c4 = (f4 & 7) << 2;
        long gr = row0 + row;
        xr[s] = make_float4(0.f, 0.f, 0.f, 0.f);
        if (gr < N && c4 < F_IN) xr[s] = *(const float4*)(x + gr * F_IN + c4);
        int idx = tid + (s << 8);
        w1r[s] = W1[(long)(idx >> 5) * 32 + (idx & 31)];
    }

    for (int kc = 0; kc < 512; kc += 32) {
        __syncthreads();
        #pragma unroll
        for (int s = 0; s < 4; ++s) {
            int f4 = tid + (s << 8);
            int row = f4 >> 3;
            int c4 = (f4 & 7) << 2;
            xs[row][c4 + 0] = xr[s].x;
            xs[row][c4 + 1] = xr[s].y;
            xs[row][c4 + 2] = xr[s].z;
            xs[row][c4 + 3] = xr[s].w;
            int idx = tid + (s << 8);
            w1s[idx >> 5][idx & 31] = w1r[s];
        }
        __syncthreads();

        int kn = kc + 32;
        if (kn < 512) {
            #pragma unroll
            for (int s = 0; s < 4; ++s) {
                int f4 = tid + (s << 8);
                int row = f4 >> 3;
                int c4 = (f4 & 7) << 2;
                long gr = row0 + row;
                int k = kn + c4;
                xr[s] = make_float4(0.f, 0.f, 0.f, 0.f);
                if (gr < N && k < F_IN) xr[s] = *(const float4*)(x + gr * F_IN + k);
                int idx = tid + (s << 8);
                int kk = kn + (idx >> 5);
                w1r[s] = (kk < F_IN) ? W1[(long)kk * 32 + (idx & 31)] : 0.f;
            }
        }

        #pragma unroll 8
        for (int kk = 0; kk < 32; ++kk) {
            float4 wa = *(const float4*)&w1s[kk][ct * 8];
            float4 wb = *(const float4*)&w1s[kk][ct * 8 + 4];
            float x0 = xs[rt * 2 + 0][kk];
            float x1 = xs[rt * 2 + 1][kk];
            acc[0][0] += x0 * wa.x; acc[0][1] += x0 * wa.y;
            acc[0][2] += x0 * wa.z; acc[0][3] += x0 * wa.w;
            acc[0][4] += x0 * wb.x; acc[0][5] += x0 * wb.y;
            acc[0][6] += x0 * wb.z; acc[0][7] += x0 * wb.w;
            acc[1][0] += x1 * wa.x; acc[1][1] += x1 * wa.y;
            acc[1][2] += x1 * wa.z; acc[1][3] += x1 * wa.w;
            acc[1][4] += x1 * wb.x; acc[1][5] += x1 * wb.y;
            acc[1][6] += x1 * wb.z; acc[1][7] += x1 * wb.w;
        }
    }

    float4 ba = *(const float4*)(b1 + ct * 8);
    float4 bb = *(const float4*)(b1 + ct * 8 + 4);
    #pragma unroll
    for (int q = 0; q < 2; ++q) {
        long gr = row0 + rt * 2 + q;
        float4 oa, ob;
        oa.x = fmaxf(acc[q][0] + ba.x, 0.f);
        oa.y = fmaxf(acc[q][1] + ba.y, 0.f);
        oa.z = fmaxf(acc[q][2] + ba.z, 0.f);
        oa.w = fmaxf(acc[q][3] + ba.w, 0.f);
        ob.x = fmaxf(acc[q][4] + bb.x, 0.f);
        ob.y = fmaxf(acc[q][5] + bb.y, 0.f);
        ob.z = fmaxf(acc[q][6] + bb.z, 0.f);
        ob.w = fmaxf(acc[q][7] + bb.w, 0.f);
        float ss = oa.x * oa.x + oa.y * oa.y + oa.z * oa.z + oa.w * oa.w
                 + ob.x * ob.x + ob.y * ob.y + ob.z * ob.z + ob.w * ob.w;
        ss += __shfl_xor(ss, 1);
        ss += __shfl_xor(ss, 2);
        if (gr < N) {
            float* op = h1 + gr * 32 + ct * 8;
            *(float4*)op = oa;
            *(float4*)(op + 4) = ob;
            if (ct == 0) rn[gr] = rsqrtf(ss + 1e-12f);
        }
    }
}

// ---------------- fused AGNN conv: weights + aggregate in one pass ----------------
__global__ __launch_bounds__(256) void conv_kernel(const float* __restrict__ h,
                                                   const float* __restrict__ rn,
                                                   const int* __restrict__ rowptr,
                                                   const int* __restrict__ col,
                                                   const float* __restrict__ betaPtr,
                                                   float* __restrict__ out,
                                                   float* __restrict__ rnOut, int N) {
    int sub = threadIdx.x & 7;
    int i = blockIdx.x * 32 + (threadIdx.x >> 3);
    if (i >= N) return;
    float beta = betaPtr ? betaPtr[0] : 1.0f;
    float shift = fabsf(beta);
    long lsub = (long)(sub << 2);
    float4 hi = *(const float4*)(h + ((long)i << 5) + lsub);
    float bri = beta * rn[i];
    int e0 = rowptr[i];
    int e1 = rowptr[i + 1];

    float s = 0.f;
    float4 acc = make_float4(0.f, 0.f, 0.f, 0.f);
    int e = e0;
    for (; e + 4 <= e1; e += 4) {
        int j0 = col[e + 0], j1 = col[e + 1], j2 = col[e + 2], j3 = col[e + 3];
        float r0 = rn[j0], r1 = rn[j1], r2 = rn[j2], r3 = rn[j3];
        float4 v0 = *(const float4*)(h + ((long)j0 << 5) + lsub);
        float4 v1 = *(const float4*)(h + ((long)j1 << 5) + lsub);
        float4 v2 = *(const float4*)(h + ((long)j2 << 5) + lsub);
        float4 v3 = *(const float4*)(h + ((long)j3 << 5) + lsub);
        float d0 = hi.x * v0.x + hi.y * v0.y + hi.z * v0.z + hi.w * v0.w;
        float d1 = hi.x * v1.x + hi.y * v1.y + hi.z * v1.z + hi.w * v1.w;
        float d2 = hi.x * v2.x + hi.y * v2.y + hi.z * v2.z + hi.w * v2.w;
        float d3 = hi.x * v3.x + hi.y * v3.y + hi.z * v3.z + hi.w * v3.w;
        d0 += __shfl_xor(d0, 1); d1 += __shfl_xor(d1, 1);
        d2 += __shfl_xor(d2, 1); d3 += __shfl_xor(d3, 1);
        d0 += __shfl_xor(d0, 2); d1 += __shfl_xor(d1, 2);
        d2 += __shfl_xor(d2, 2); d3 += __shfl_xor(d3, 2);
        d0 += __shfl_xor(d0, 4); d1 += __shfl_xor(d1, 4);
        d2 += __shfl_xor(d2, 4); d3 += __shfl_xor(d3, 4);
        float w0 = __expf(bri * r0 * d0 - shift);
        float w1 = __expf(bri * r1 * d1 - shift);
        float w2 = __expf(bri * r2 * d2 - shift);
        float w3 = __expf(bri * r3 * d3 - shift);
        s += (w0 + w1) + (w2 + w3);
        acc.x += w0 * v0.x + w1 * v1.x + w2 * v2.x + w3 * v3.x;
        acc.y += w0 * v0.y + w1 * v1.y + w2 * v2.y + w3 * v3.y;
        acc.z += w0 * v0.z + w1 * v1.z + w2 * v2.z + w3 * v3.z;
        acc.w += w0 * v0.w + w1 * v1.w + w2 * v2.w + w3 * v3.w;
    }
    for (; e < e1; ++e) {
        int j = col[e];
        float rj = rn[j];
        float4 v = *(const float4*)(h + ((long)j << 5) + lsub);
        float d = hi.x * v.x + hi.y * v.y + hi.z * v.z + hi.w * v.w;
        d += __shfl_xor(d, 1);
        d += __shfl_xor(d, 2);
        d += __shfl_xor(d, 4);
        float w = __expf(bri * rj * d - shift);
        s += w;
        acc.x += w * v.x; acc.y += w * v.y; acc.z += w * v.z; acc.w += w * v.w;
    }

    float inv = 1.f / (s + 1e-16f);
    float4 o = make_float4(acc.x * inv, acc.y * inv, acc.z * inv, acc.w * inv);
    *(float4*)(out + ((long)i << 5) + lsub) = o;
    if (rnOut) {
        float ss = o.x * o.x + o.y * o.y + o.z * o.z + o.w * o.w;
        ss += __shfl_xor(ss, 1);
        ss += __shfl_xor(ss, 2);
        ss += __shfl_xor(ss, 4);
        if (sub == 0) rnOut[i] = rsqrtf(ss + 1e-12f);
    }
}

// ---------------- GEMM2: out = h3 @ W2 + b2, [N,32]@[32,40] ----------------
__global__ __launch_bounds__(256) void gemm2_kernel(const float* __restrict__ h3,
                                                    const float* __restrict__ W2,
                                                    const float* __restrict__ b2,
                                                    float* __restrict__ out, int N) {
    __shared__ float w2s[HID * NCLS];
    __shared__ float b2s[NCLS];
    for (int i = threadIdx.x; i < HID * NCLS; i += 256) w2s[i] = W2[i];
    if (threadIdx.x < NCLS) b2s[threadIdx.x] = b2[threadIdx.x];
    __syncthreads();

    int idx = blockIdx.x * 256 + threadIdx.x;
    if (idx >= N * NCLS) return;
    int n = idx / NCLS;
    int c = idx - n * NCLS;

    const float4* hp = (const float4*)(h3 + (long)n * 32);
    float acc = b2s[c];
    #pragma unroll
    for (int k4 = 0; k4 < 8; ++k4) {
        float4 hv = hp[k4];
        acc += hv.x * w2s[(k4 * 4 + 0) * NCLS + c];
        acc += hv.y * w2s[(k4 * 4 + 1) * NCLS + c];
        acc += hv.z * w2s[(k4 * 4 + 2) * NCLS + c];
        acc += hv.w * w2s[(k4 * 4 + 3) * NCLS + c];
    }
    out[idx] = acc;
}

// ---------------- launch ----------------

extern "C" void kernel_launch(void* const* d_in, const int* in_sizes, int n_in,
                              void* d_out, int out_size, void* d_ws, size_t ws_size,
                              hipStream_t stream) {
    const float* x     = (const float*)d_in[0];
    const float* W1    = (const float*)d_in[1];
    const float* b1    = (const float*)d_in[2];
    const float* W2    = (const float*)d_in[3];
    const float* b2    = (const float*)d_in[4];
    const float* beta2 = (const float*)d_in[5];
    const int*   ei    = (const int*)d_in[6];

    int N = in_sizes[0] / F_IN;        // 100000
    int E = in_sizes[6] / 2;           // 1700000
    const int* src = ei;
    const int* dst = ei + E;
    float* out = (float*)d_out;

    // workspace carve (256B aligned)
    char* p = (char*)d_ws;
    auto alloc = [&](size_t bytes) -> void* {
        void* r = (void*)p;
        p += (bytes + 255) & ~(size_t)255;
        return r;
    };
    float* h1  = (float*)alloc((size_t)N * 32 * 4);
    float* h2  = (float*)alloc((size_t)N * 32 * 4);
    float* rn1 = (float*)alloc((size_t)N * 4);
    float* rn2 = (float*)alloc((size_t)N * 4);
    int* rowptr    = (int*)alloc((size_t)(N + 1) * 4);
    int* col       = (int*)alloc((size_t)E * 4);
    int* gstage    = (int*)alloc((size_t)E * 4);
    int* gcnt      = (int*)alloc((size_t)MAXB * 4);
    int* bucketptr = (int*)alloc((size_t)(MAXB + 1) * 4);
    int* bcur      = (int*)alloc((size_t)MAXB * 4);
    float* h3 = h1;                    // conv2 output reuses h1 (free by then)

    int nb = (N + NPB - 1) / NPB;      // 391 buckets
    int p1blocks = (int)(((long)E + EPB - 1) / EPB);  // 104
    int cblocks = (N + 31) / 32;       // conv: 8 lanes/node

    gemm1_kernel<<<(N + 127) / 128, 256, 0, stream>>>(x, W1, b1, h1, rn1, N);

    // CSR build: count -> scan -> bin (staged, coalesced) -> per-bucket scatter
    hipMemsetAsync(gcnt, 0, (size_t)nb * 4, stream);
    csr_count_kernel<<<p1blocks, 256, 0, stream>>>(dst, E, gcnt, nb);
    csr_bscan_kernel<<<1, 512, 0, stream>>>(gcnt, bucketptr, bcur, nb);
    csr_bin_kernel<<<p1blocks, 512, 0, stream>>>(src, dst, E, bcur, gstage, nb);
    csr_scatter_kernel<<<nb, 256, 0, stream>>>(bucketptr, gstage, rowptr, col, N, nb);

    conv_kernel<<<cblocks, 256, 0, stream>>>(h1, rn1, rowptr, col, nullptr, h2, rn2, N);
    conv_kernel<<<cblocks, 256, 0, stream>>>(h2, rn2, rowptr, col, beta2, h3, nullptr, N);

    gemm2_kernel<<<(N * NCLS + 255) / 256, 256, 0, stream>>>(h3, W2, b2, out, N);
}